// Round 17
// baseline (420.117 us; speedup 1.0000x reference)
//
#include <hip/hip_runtime.h>
#include <hip/hip_cooperative_groups.h>
namespace cg = cooperative_groups;

#define E_TOT 320000
#define NN    10000
#define DN    128
#define DE    32
#define DH    192
#define DO    128
#define EB    64
#define SHS   196   // s_h row stride in ushorts (392 B)
#define CGRID 1024  // cooperative grid: 4 blocks/CU x 256 CUs

typedef __attribute__((ext_vector_type(8))) short bf16x8;
typedef __attribute__((ext_vector_type(4))) float f32x4;

#define W1_FRAGS (8*12*64)
#define E_FRAGS  (12*64)
#define W2_FRAGS (6*8*64)
#define FRAGS_TOT (W1_FRAGS + E_FRAGS + W2_FRAGS)
#define ZH (NN * DH / 4)
#define PREP_TOT (FRAGS_TOT + ZH + E_TOT)
__device__ __align__(16) unsigned short g_p1[W1_FRAGS * 8];
__device__ __align__(16) unsigned short g_e [E_FRAGS * 8];
__device__ __align__(16) unsigned short g_p2[W2_FRAGS * 8];

__device__ __forceinline__ unsigned short f2bf(float f) {
    union { float f; unsigned u; } v; v.f = f;
    return (unsigned short)((v.u + 0x7FFFu + ((v.u >> 16) & 1u)) >> 16);
}
__device__ __forceinline__ float bflo(unsigned u) {
    union { unsigned v; float f; } t; t.v = u << 16; return t.f;
}
__device__ __forceinline__ float bfhi(unsigned u) {
    union { unsigned v; float f; } t; t.v = u & 0xFFFF0000u; return t.f;
}
__device__ __forceinline__ float bf2f(unsigned short s) {
    union { unsigned v; float f; } t; t.v = (unsigned)s << 16; return t.f;
}
__device__ __forceinline__ float tanh_fast(float x) {
    float ex = __expf(x + x);
    return 1.0f - 2.0f * __builtin_amdgcn_rcpf(ex + 1.0f);
}
__device__ __forceinline__ unsigned cvt_pk_bf16(float lo, float hi) {
    unsigned r;
    asm("v_cvt_pk_bf16_f32 %0, %1, %2" : "=v"(r) : "v"(lo), "v"(hi));
    return r;
}

// ===========================================================================
// Phase bodies (shared between the cooperative kernel and the fallback path)
// ===========================================================================
__device__ __forceinline__ void dev_prep_item(
    int f, const float* __restrict__ W1, const float* __restrict__ W2,
    const int* __restrict__ senders, float* __restrict__ Hbar,
    int* __restrict__ row_start)
{
    unsigned short tmp[8];
    if (f < W1_FRAGS) {
        int kk = f / (12 * 64), nt = (f >> 6) % 12, lane = f & 63;
        int r0 = kk * 32 + ((lane >> 4) << 3);
        int c  = nt * 16 + (lane & 15);
        #pragma unroll
        for (int i = 0; i < 8; ++i) tmp[i] = f2bf(W1[(r0 + i) * DH + c]);
        *(uint4*)(g_p1 + (size_t)f * 8) = *(const uint4*)tmp;
    } else if (f < W1_FRAGS + E_FRAGS) {
        int f2 = f - W1_FRAGS;
        int mt = f2 >> 6, lane = f2 & 63;
        int k0 = ((lane >> 4) << 3);
        int hid = mt * 16 + (lane & 15);
        #pragma unroll
        for (int i = 0; i < 8; ++i) tmp[i] = f2bf(W1[(256 + k0 + i) * DH + hid]);
        *(uint4*)(g_e + (size_t)f2 * 8) = *(const uint4*)tmp;
    } else if (f < FRAGS_TOT) {
        int f3 = f - W1_FRAGS - E_FRAGS;
        int kk = f3 / (8 * 64), nt = (f3 >> 6) % 8, lane = f3 & 63;
        int r0 = kk * 32 + ((lane >> 4) << 3);
        int c  = nt * 16 + (lane & 15);
        #pragma unroll
        for (int i = 0; i < 8; ++i) tmp[i] = f2bf(W2[(r0 + i) * DO + c]);
        *(uint4*)(g_p2 + (size_t)f3 * 8) = *(const uint4*)tmp;
    } else if (f < FRAGS_TOT + ZH) {
        ((float4*)Hbar)[f - FRAGS_TOT] = make_float4(0.f, 0.f, 0.f, 0.f);
    } else if (f < PREP_TOT) {
        int e = f - FRAGS_TOT - ZH;
        int s_cur  = senders[e];
        int s_prev = (e == 0) ? -1 : senders[e - 1];
        if (s_prev != s_cur)
            for (int n = s_prev + 1; n <= s_cur; ++n) row_start[n] = e;
        if (e == E_TOT - 1)
            for (int n = s_cur + 1; n <= NN; ++n) row_start[n] = E_TOT;
    }
}

// bx in [0, 314): half = bx&1, node tile = bx>>1
__device__ __forceinline__ void dev_node_proj(
    int bx, int tid, const float* __restrict__ n_embed,
    const float* __restrict__ b1, unsigned short* __restrict__ P,
    unsigned short (*s_a)[136])
{
    const int half = bx & 1;
    const int n0   = (bx >> 1) * 64;

    #pragma unroll
    for (int it = 0; it < 8; ++it) {
        int idx = tid + it * 256;
        int row = idx >> 5, c = idx & 31;
        float4 v = make_float4(0.f, 0.f, 0.f, 0.f);
        if (n0 + row < NN) v = ((const float4*)(n_embed + (size_t)(n0 + row) * DN))[c];
        unsigned t0 = cvt_pk_bf16(v.x, v.y), t1 = cvt_pk_bf16(v.z, v.w);
        *(uint2*)&s_a[row][c * 4] = make_uint2(t0, t1);
    }
    __syncthreads();

    const int lane = tid & 63, w = tid >> 6;
    const int arow = lane & 15, akb = (lane >> 4) * 8, rbase = (lane >> 4) * 4;

    f32x4 acc[4][3];
    #pragma unroll
    for (int mt = 0; mt < 4; ++mt)
        #pragma unroll
        for (int j = 0; j < 3; ++j) acc[mt][j] = (f32x4){0.f, 0.f, 0.f, 0.f};

    for (int kk = 0; kk < 4; ++kk) {
        bf16x8 a[4], b[3];
        #pragma unroll
        for (int mt = 0; mt < 4; ++mt)
            a[mt] = *(const bf16x8*)&s_a[mt * 16 + arow][kk * 32 + akb];
        #pragma unroll
        for (int j = 0; j < 3; ++j)
            b[j] = *(const bf16x8*)(g_p1 + (((size_t)(kk + 4 * half) * 12 + (3 * w + j)) * 64 + lane) * 8);
        #pragma unroll
        for (int mt = 0; mt < 4; ++mt)
            #pragma unroll
            for (int j = 0; j < 3; ++j)
                acc[mt][j] = __builtin_amdgcn_mfma_f32_16x16x32_bf16(a[mt], b[j], acc[mt][j], 0, 0, 0);
    }

    unsigned short* Pout = P + (size_t)half * NN * DH;
    float bj[3];
    #pragma unroll
    for (int j = 0; j < 3; ++j) bj[j] = (half == 0) ? b1[48 * w + 16 * j + arow] : 0.f;
    const int gq = arow >> 2, ii = arow & 3;
    #pragma unroll
    for (int mt = 0; mt < 4; ++mt)
        #pragma unroll
        for (int j = 0; j < 3; ++j)
            #pragma unroll
            for (int r = 0; r < 4; ++r) {
                int row = n0 + mt * 16 + rbase + r;
                if (row < NN)
                    Pout[((size_t)row * 4 + gq) * 48 + (3 * w + j) * 4 + ii] =
                        f2bf(acc[mt][j][r] + bj[j]);
            }
}

__device__ __forceinline__ void dev_edge_tile(
    int e0, int tid, const float* __restrict__ e_embed,
    const int* __restrict__ senders, const int* __restrict__ receivers,
    const unsigned short* __restrict__ Ps, const unsigned short* __restrict__ Pr,
    float* __restrict__ Hbar, unsigned short (*s_h)[SHS], int* s_send)
{
    const int lane = tid & 63, w = tid >> 6;
    const int arow = lane & 15, g = lane >> 4;

    const int myedge = e0 + w * 16 + arow;
    const int sN = senders[myedge], rN = receivers[myedge];
    const unsigned short* psbase = Ps + ((size_t)sN * 4 + g) * 48;
    const unsigned short* prbase = Pr + ((size_t)rN * 4 + g) * 48;
    uint4 psq[6], prq[6];
    #pragma unroll
    for (int j = 0; j < 6; ++j) {
        psq[j] = *(const uint4*)(psbase + j * 8);
        prq[j] = *(const uint4*)(prbase + j * 8);
    }
    union { bf16x8 v; unsigned u[4]; } bfr;
    {
        const float* erow = e_embed + (size_t)myedge * DE + g * 8;
        float4 ev0 = *(const float4*)erow;
        float4 ev1 = *(const float4*)(erow + 4);
        bfr.u[0] = cvt_pk_bf16(ev0.x, ev0.y);
        bfr.u[1] = cvt_pk_bf16(ev0.z, ev0.w);
        bfr.u[2] = cvt_pk_bf16(ev1.x, ev1.y);
        bfr.u[3] = cvt_pk_bf16(ev1.z, ev1.w);
    }
    if (tid < EB) s_send[tid] = senders[e0 + tid];

    #pragma unroll
    for (int mt = 0; mt < 12; ++mt) {
        unsigned px, py, qx, qy;
        if ((mt & 1) == 0) {
            px = psq[mt >> 1].x; py = psq[mt >> 1].y;
            qx = prq[mt >> 1].x; qy = prq[mt >> 1].y;
        } else {
            px = psq[mt >> 1].z; py = psq[mt >> 1].w;
            qx = prq[mt >> 1].z; qy = prq[mt >> 1].w;
        }
        f32x4 cinit;
        cinit[0] = bflo(px) + bflo(qx);
        cinit[1] = bfhi(px) + bfhi(qx);
        cinit[2] = bflo(py) + bflo(qy);
        cinit[3] = bfhi(py) + bfhi(qy);
        bf16x8 af = *(const bf16x8*)(g_e + ((size_t)mt * 64 + lane) * 8);
        f32x4 acc = __builtin_amdgcn_mfma_f32_16x16x32_bf16(af, bfr.v, cinit, 0, 0, 0);
        float t0 = tanh_fast(acc[0]);
        float t1 = tanh_fast(acc[1]);
        float t2 = tanh_fast(acc[2]);
        float t3 = tanh_fast(acc[3]);
        *(uint2*)&s_h[w * 16 + arow][mt * 16 + g * 4] =
            make_uint2(cvt_pk_bf16(t0, t1), cvt_pk_bf16(t2, t3));
    }
    __syncthreads();

    if (tid < DH) {
        const int c = tid;
        float sum = 0.f;
        int cur = s_send[0];
        #pragma unroll 8
        for (int e = 0; e < EB; ++e) {
            sum += bf2f(s_h[e][c]);
            int nxt = (e + 1 < EB) ? s_send[e + 1] : -1;
            if (nxt != cur) {
                atomicAdd(&Hbar[(size_t)cur * DH + c], sum);
                sum = 0.f;
                cur = nxt;
            }
        }
    }
}

// bx in [0, 157)
__device__ __forceinline__ void dev_node_out(
    int bx, int tid, const float* __restrict__ Hbar,
    const int* __restrict__ row_start, const float* __restrict__ b2,
    float* __restrict__ out)
{
    const int lane = tid & 63, w = tid >> 6;
    const int n0   = (bx * 4 + w) * 16;
    if (n0 >= NN) return;
    const int arow = lane & 15, akb = (lane >> 4) * 8, rbase = (lane >> 4) * 4;

    const int myrow = (n0 + arow < NN) ? (n0 + arow) : (NN - 1);
    const int cnt = row_start[myrow + 1] - row_start[myrow];
    const float ic = (cnt > 0) ? 1.0f / (float)cnt : 0.0f;

    const float* hrow = Hbar + (size_t)myrow * DH;
    union { bf16x8 v; unsigned u[4]; } a[6];
    #pragma unroll
    for (int kk = 0; kk < 6; ++kk) {
        float4 v0 = *(const float4*)(hrow + kk * 32 + akb);
        float4 v1 = *(const float4*)(hrow + kk * 32 + akb + 4);
        a[kk].u[0] = cvt_pk_bf16(v0.x * ic, v0.y * ic);
        a[kk].u[1] = cvt_pk_bf16(v0.z * ic, v0.w * ic);
        a[kk].u[2] = cvt_pk_bf16(v1.x * ic, v1.y * ic);
        a[kk].u[3] = cvt_pk_bf16(v1.z * ic, v1.w * ic);
    }

    f32x4 acc[8];
    #pragma unroll
    for (int j = 0; j < 8; ++j) acc[j] = (f32x4){0.f, 0.f, 0.f, 0.f};

    #pragma unroll
    for (int kk = 0; kk < 6; ++kk)
        #pragma unroll
        for (int j = 0; j < 8; ++j) {
            bf16x8 b = *(const bf16x8*)(g_p2 + (((size_t)kk * 8 + j) * 64 + lane) * 8);
            acc[j] = __builtin_amdgcn_mfma_f32_16x16x32_bf16(a[kk].v, b, acc[j], 0, 0, 0);
        }

    #pragma unroll
    for (int j = 0; j < 8; ++j) {
        const float bd = b2[j * 16 + arow];
        #pragma unroll
        for (int r = 0; r < 4; ++r) {
            int row = n0 + rbase + r;
            if (row < NN)
                out[(size_t)row * DO + j * 16 + arow] = acc[j][r] + bd;
        }
    }
}

// ===========================================================================
// Cooperative fused kernel: A(prep) -> B(node_proj) -> C(edge) -> D(node_out)
// ===========================================================================
__global__ __launch_bounds__(256, 4) void fused_all(
    const float* __restrict__ n_embed, const float* __restrict__ e_embed,
    const int* __restrict__ senders, const int* __restrict__ receivers,
    const float* __restrict__ W1, const float* __restrict__ b1,
    const float* __restrict__ W2, const float* __restrict__ b2,
    unsigned short* __restrict__ Ps, unsigned short* __restrict__ Pr,
    float* __restrict__ Hbar, int* __restrict__ row_start,
    float* __restrict__ out)
{
    __shared__ __align__(16) char s_u[EB * SHS * 2];   // 25088 B (s_a / s_h union)
    __shared__ int s_send[EB];
    unsigned short (*s_a)[136] = (unsigned short(*)[136])s_u;
    unsigned short (*s_h)[SHS] = (unsigned short(*)[SHS])s_u;

    cg::grid_group gg = cg::this_grid();
    const int tid = threadIdx.x;

    // ---- phase A: pack weights + zero Hbar + row_start ----
    for (int f = blockIdx.x * 256 + tid; f < PREP_TOT; f += CGRID * 256)
        dev_prep_item(f, W1, W2, senders, Hbar, row_start);
    gg.sync();

    // ---- phase B: node projections (314 logical blocks) ----
    if (blockIdx.x < (NN + 63) / 64 * 2)
        dev_node_proj(blockIdx.x, tid, n_embed, b1, Ps, s_a);
    gg.sync();

    // ---- phase C: edge tiles, XCD-contiguous mapping (8 x 625 = 5000) ----
    {
        const int xcd = blockIdx.x & 7, loc = blockIdx.x >> 3;   // loc 0..127
        for (int t = loc; t < 625; t += CGRID / 8) {
            dev_edge_tile((xcd * 625 + t) * EB, tid, e_embed, senders, receivers,
                          Ps, Pr, Hbar, s_h, s_send);
            __syncthreads();   // s_h/s_send safe to overwrite next iteration
        }
    }
    gg.sync();

    // ---- phase D: node_out (157 logical blocks) ----
    if (blockIdx.x < (NN + 63) / 64)
        dev_node_out(blockIdx.x, tid, Hbar, row_start, b2, out);
}

// ===========================================================================
// Fallback path (R15 structure) in case cooperative launch is unavailable
// ===========================================================================
__global__ void prep_k(const float* __restrict__ W1, const float* __restrict__ W2,
                       const int* __restrict__ senders,
                       float* __restrict__ Hbar, int* __restrict__ row_start)
{
    int f = blockIdx.x * 256 + threadIdx.x;
    if (f < PREP_TOT) dev_prep_item(f, W1, W2, senders, Hbar, row_start);
}

__global__ __launch_bounds__(256) void node_proj_k(
    const float* __restrict__ n_embed, const float* __restrict__ b1,
    unsigned short* __restrict__ P)
{
    __shared__ __align__(16) unsigned short s_a[64][136];
    dev_node_proj(blockIdx.x, threadIdx.x, n_embed, b1, P, s_a);
}

__global__ __launch_bounds__(256) void edge_reduce_k(
    const float* __restrict__ e_embed,
    const int* __restrict__ senders, const int* __restrict__ receivers,
    const unsigned short* __restrict__ Ps, const unsigned short* __restrict__ Pr,
    float* __restrict__ Hbar)
{
    __shared__ __align__(16) unsigned short s_h[EB][SHS];
    __shared__ int s_send[EB];
    const int nb8 = gridDim.x >> 3;
    const int e0  = (((blockIdx.x & 7) * nb8) + (blockIdx.x >> 3)) * EB;
    dev_edge_tile(e0, threadIdx.x, e_embed, senders, receivers, Ps, Pr, Hbar,
                  s_h, s_send);
}

__global__ __launch_bounds__(256) void node_out_k(
    const float* __restrict__ Hbar, const int* __restrict__ row_start,
    const float* __restrict__ b2, float* __restrict__ out)
{
    dev_node_out(blockIdx.x, threadIdx.x, Hbar, row_start, b2, out);
}

extern "C" void kernel_launch(void* const* d_in, const int* in_sizes, int n_in,
                              void* d_out, int out_size, void* d_ws, size_t ws_size,
                              hipStream_t stream)
{
    const float* n_embed   = (const float*)d_in[0];
    const float* e_embed   = (const float*)d_in[1];
    const int*   senders   = (const int*)d_in[2];
    const int*   receivers = (const int*)d_in[3];
    const float* W1        = (const float*)d_in[4];
    const float* b1        = (const float*)d_in[5];
    const float* W2        = (const float*)d_in[6];
    const float* b2        = (const float*)d_in[7];
    float* out = (float*)d_out;

    unsigned short* Ps   = (unsigned short*)d_ws;                // [NN][192] bf16
    unsigned short* Pr   = Ps + (size_t)NN * DH;                 // [NN][192] bf16
    float*          Hbar = (float*)(Pr + (size_t)NN * DH);       // [NN][192] f32
    int*            row_start = (int*)(Hbar + (size_t)NN * DH);  // [NN+1]

    void* args[] = { (void*)&n_embed, (void*)&e_embed, (void*)&senders,
                     (void*)&receivers, (void*)&W1, (void*)&b1, (void*)&W2,
                     (void*)&b2, (void*)&Ps, (void*)&Pr, (void*)&Hbar,
                     (void*)&row_start, (void*)&out };
    hipError_t err = hipLaunchCooperativeKernel((void*)fused_all,
                         dim3(CGRID), dim3(256), args, 0, stream);
    if (err != hipSuccess) {
        // graceful fallback: the green R15 4-kernel chain
        prep_k<<<(PREP_TOT + 255) / 256, 256, 0, stream>>>(W1, W2, senders, Hbar, row_start);
        node_proj_k<<<(NN + 63) / 64 * 2, 256, 0, stream>>>(n_embed, b1, Ps);
        edge_reduce_k<<<E_TOT / EB, 256, 0, stream>>>(e_embed, senders, receivers, Ps, Pr, Hbar);
        node_out_k<<<(NN + 63) / 64, 256, 0, stream>>>(Hbar, row_start, b2, out);
    }
}

// Round 18
// 85.597 us; speedup vs baseline: 4.9081x; 4.9081x over previous
//
#include <hip/hip_runtime.h>

#define E_TOT 320000
#define NN    10000
#define DN    128
#define DE    32
#define DH    192
#define DO    128
#define EB    64
#define SHT   72    // s_hT row stride in ushorts (144 B, 16B-aligned rows)

typedef __attribute__((ext_vector_type(8))) short bf16x8;
typedef __attribute__((ext_vector_type(4))) float f32x4;

#define W1_FRAGS (8*12*64)
#define E_FRAGS  (12*64)
#define W2_FRAGS (6*8*64)
#define FRAGS_TOT (W1_FRAGS + E_FRAGS + W2_FRAGS)
#define ZH (NN * DH / 4)
__device__ __align__(16) unsigned short g_p1[W1_FRAGS * 8];
__device__ __align__(16) unsigned short g_e [E_FRAGS * 8];
__device__ __align__(16) unsigned short g_p2[W2_FRAGS * 8];

__device__ __forceinline__ unsigned short f2bf(float f) {
    union { float f; unsigned u; } v; v.f = f;
    return (unsigned short)((v.u + 0x7FFFu + ((v.u >> 16) & 1u)) >> 16);
}
__device__ __forceinline__ float bflo(unsigned u) {
    union { unsigned v; float f; } t; t.v = u << 16; return t.f;
}
__device__ __forceinline__ float bfhi(unsigned u) {
    union { unsigned v; float f; } t; t.v = u & 0xFFFF0000u; return t.f;
}
__device__ __forceinline__ float tanh_fast(float x) {
    float ex = __expf(x + x);
    return 1.0f - 2.0f * __builtin_amdgcn_rcpf(ex + 1.0f);
}
__device__ __forceinline__ unsigned cvt_pk_bf16(float lo, float hi) {
    unsigned r;
    asm("v_cvt_pk_bf16_f32 %0, %1, %2" : "=v"(r) : "v"(lo), "v"(hi));
    return r;
}

// ---------------------------------------------------------------------------
// prep: pack weight tables + zero Hbar + build row_start[0..NN]  (= R15)
// ---------------------------------------------------------------------------
__global__ void prep(const float* __restrict__ W1, const float* __restrict__ W2,
                     const int* __restrict__ senders,
                     float* __restrict__ Hbar, int* __restrict__ row_start)
{
    int f = blockIdx.x * 256 + threadIdx.x;
    unsigned short tmp[8];
    if (f < W1_FRAGS) {
        int kk = f / (12 * 64), nt = (f >> 6) % 12, lane = f & 63;
        int r0 = kk * 32 + ((lane >> 4) << 3);
        int c  = nt * 16 + (lane & 15);
        #pragma unroll
        for (int i = 0; i < 8; ++i) tmp[i] = f2bf(W1[(r0 + i) * DH + c]);
        *(uint4*)(g_p1 + (size_t)f * 8) = *(const uint4*)tmp;
    } else if (f < W1_FRAGS + E_FRAGS) {
        int f2 = f - W1_FRAGS;
        int mt = f2 >> 6, lane = f2 & 63;
        int k0 = ((lane >> 4) << 3);
        int hid = mt * 16 + (lane & 15);
        #pragma unroll
        for (int i = 0; i < 8; ++i) tmp[i] = f2bf(W1[(256 + k0 + i) * DH + hid]);
        *(uint4*)(g_e + (size_t)f2 * 8) = *(const uint4*)tmp;
    } else if (f < FRAGS_TOT) {
        int f3 = f - W1_FRAGS - E_FRAGS;
        int kk = f3 / (8 * 64), nt = (f3 >> 6) % 8, lane = f3 & 63;
        int r0 = kk * 32 + ((lane >> 4) << 3);
        int c  = nt * 16 + (lane & 15);
        #pragma unroll
        for (int i = 0; i < 8; ++i) tmp[i] = f2bf(W2[(r0 + i) * DO + c]);
        *(uint4*)(g_p2 + (size_t)f3 * 8) = *(const uint4*)tmp;
    } else if (f < FRAGS_TOT + ZH) {
        ((float4*)Hbar)[f - FRAGS_TOT] = make_float4(0.f, 0.f, 0.f, 0.f);
    } else if (f < FRAGS_TOT + ZH + E_TOT) {
        int e = f - FRAGS_TOT - ZH;
        int s_cur  = senders[e];
        int s_prev = (e == 0) ? -1 : senders[e - 1];
        if (s_prev != s_cur)
            for (int n = s_prev + 1; n <= s_cur; ++n) row_start[n] = e;
        if (e == E_TOT - 1)
            for (int n = s_cur + 1; n <= NN; ++n) row_start[n] = E_TOT;
    }
}

// ---------------------------------------------------------------------------
// node projections (lane-contiguous P' layout)  (= R15)
// ---------------------------------------------------------------------------
__global__ __launch_bounds__(256) void node_proj(
    const float* __restrict__ n_embed, const float* __restrict__ b1,
    unsigned short* __restrict__ P)
{
    __shared__ __align__(16) unsigned short s_a[64][136];
    const int tid  = threadIdx.x;
    const int half = blockIdx.y;
    const int n0   = blockIdx.x * 64;

    #pragma unroll
    for (int it = 0; it < 8; ++it) {
        int idx = tid + it * 256;
        int row = idx >> 5, c = idx & 31;
        float4 v = make_float4(0.f, 0.f, 0.f, 0.f);
        if (n0 + row < NN) v = ((const float4*)(n_embed + (size_t)(n0 + row) * DN))[c];
        unsigned t0 = cvt_pk_bf16(v.x, v.y), t1 = cvt_pk_bf16(v.z, v.w);
        *(uint2*)&s_a[row][c * 4] = make_uint2(t0, t1);
    }
    __syncthreads();

    const int lane = tid & 63, w = tid >> 6;
    const int arow = lane & 15, akb = (lane >> 4) * 8, rbase = (lane >> 4) * 4;

    f32x4 acc[4][3];
    #pragma unroll
    for (int mt = 0; mt < 4; ++mt)
        #pragma unroll
        for (int j = 0; j < 3; ++j) acc[mt][j] = (f32x4){0.f, 0.f, 0.f, 0.f};

    for (int kk = 0; kk < 4; ++kk) {
        bf16x8 a[4], b[3];
        #pragma unroll
        for (int mt = 0; mt < 4; ++mt)
            a[mt] = *(const bf16x8*)&s_a[mt * 16 + arow][kk * 32 + akb];
        #pragma unroll
        for (int j = 0; j < 3; ++j)
            b[j] = *(const bf16x8*)(g_p1 + (((size_t)(kk + 4 * half) * 12 + (3 * w + j)) * 64 + lane) * 8);
        #pragma unroll
        for (int mt = 0; mt < 4; ++mt)
            #pragma unroll
            for (int j = 0; j < 3; ++j)
                acc[mt][j] = __builtin_amdgcn_mfma_f32_16x16x32_bf16(a[mt], b[j], acc[mt][j], 0, 0, 0);
    }

    unsigned short* Pout = P + (size_t)half * NN * DH;
    float bj[3];
    #pragma unroll
    for (int j = 0; j < 3; ++j) bj[j] = (half == 0) ? b1[48 * w + 16 * j + arow] : 0.f;
    const int gq = arow >> 2, ii = arow & 3;
    #pragma unroll
    for (int mt = 0; mt < 4; ++mt)
        #pragma unroll
        for (int j = 0; j < 3; ++j)
            #pragma unroll
            for (int r = 0; r < 4; ++r) {
                int row = n0 + mt * 16 + rbase + r;
                if (row < NN)
                    Pout[((size_t)row * 4 + gq) * 48 + (3 * w + j) * 4 + ii] =
                        f2bf(acc[mt][j][r] + bj[j]);
            }
}

// ---------------------------------------------------------------------------
// edge kernel: gather + GEMM1^T (P-add in MFMA C-input) + tanh -> s_hT
// (transposed); run decomposition via ballot; segment reduce via MFMA
// against a 0/1 run-indicator matrix; masked atomic flush of C[hid][run].
// ---------------------------------------------------------------------------
__global__ __launch_bounds__(256) void edge_reduce(
    const float* __restrict__ e_embed,
    const int* __restrict__ senders, const int* __restrict__ receivers,
    const unsigned short* __restrict__ Ps, const unsigned short* __restrict__ Pr,
    float* __restrict__ Hbar)
{
    __shared__ __align__(16) unsigned short s_hT[DH][SHT];  // 27648 B
    __shared__ int s_send[EB];
    __shared__ int s_runid[EB];
    __shared__ int s_runnode[EB];
    __shared__ int s_nruns;

    const int tid  = threadIdx.x;
    const int nb8  = gridDim.x >> 3;                       // 625
    const int e0   = (((blockIdx.x & 7) * nb8) + (blockIdx.x >> 3)) * EB;
    const int lane = tid & 63, w = tid >> 6;
    const int arow = lane & 15, g = lane >> 4;

    // ---- phase 0: per-lane loads (wide, contiguous per lane) ----
    const int myedge = e0 + w * 16 + arow;
    const int sN = senders[myedge], rN = receivers[myedge];
    const unsigned short* psbase = Ps + ((size_t)sN * 4 + g) * 48;
    const unsigned short* prbase = Pr + ((size_t)rN * 4 + g) * 48;
    uint4 psq[6], prq[6];
    #pragma unroll
    for (int j = 0; j < 6; ++j) {
        psq[j] = *(const uint4*)(psbase + j * 8);
        prq[j] = *(const uint4*)(prbase + j * 8);
    }
    union { bf16x8 v; unsigned u[4]; } bfr;
    {
        const float* erow = e_embed + (size_t)myedge * DE + g * 8;
        float4 ev0 = *(const float4*)erow;
        float4 ev1 = *(const float4*)(erow + 4);
        bfr.u[0] = cvt_pk_bf16(ev0.x, ev0.y);
        bfr.u[1] = cvt_pk_bf16(ev0.z, ev0.w);
        bfr.u[2] = cvt_pk_bf16(ev1.x, ev1.y);
        bfr.u[3] = cvt_pk_bf16(ev1.z, ev1.w);
    }
    if (tid < EB) s_send[tid] = senders[e0 + tid];

    // ---- wave 0: run decomposition of the sorted 64-edge tile ----
    if (w == 0) {
        int e = lane;
        int cur  = s_send[e];
        int prev = (e == 0) ? -1 : s_send[e - 1];
        bool bnd = (prev != cur);
        unsigned long long mask = __ballot(bnd);
        int rid = __popcll(mask << (63 - e)) - 1;   // boundaries at pos <= e, minus 1
        s_runid[e] = rid;
        if (bnd) s_runnode[rid] = cur;
        if (e == 63) s_nruns = rid + 1;
    }

    // ---- phase 1: GEMM1^T, C-input = Ps+Pr; tanh -> s_hT[hid][edge] ----
    #pragma unroll
    for (int mt = 0; mt < 12; ++mt) {
        unsigned px, py, qx, qy;
        if ((mt & 1) == 0) {
            px = psq[mt >> 1].x; py = psq[mt >> 1].y;
            qx = prq[mt >> 1].x; qy = prq[mt >> 1].y;
        } else {
            px = psq[mt >> 1].z; py = psq[mt >> 1].w;
            qx = prq[mt >> 1].z; qy = prq[mt >> 1].w;
        }
        f32x4 cinit;
        cinit[0] = bflo(px) + bflo(qx);
        cinit[1] = bfhi(px) + bfhi(qx);
        cinit[2] = bflo(py) + bflo(qy);
        cinit[3] = bfhi(py) + bfhi(qy);
        bf16x8 af = *(const bf16x8*)(g_e + ((size_t)mt * 64 + lane) * 8);
        f32x4 acc = __builtin_amdgcn_mfma_f32_16x16x32_bf16(af, bfr.v, cinit, 0, 0, 0);
        unsigned u01 = cvt_pk_bf16(tanh_fast(acc[0]), tanh_fast(acc[1]));
        unsigned u23 = cvt_pk_bf16(tanh_fast(acc[2]), tanh_fast(acc[3]));
        const int ecol = w * 16 + arow;
        s_hT[mt * 16 + g * 4 + 0][ecol] = (unsigned short)(u01 & 0xFFFFu);
        s_hT[mt * 16 + g * 4 + 1][ecol] = (unsigned short)(u01 >> 16);
        s_hT[mt * 16 + g * 4 + 2][ecol] = (unsigned short)(u23 & 0xFFFFu);
        s_hT[mt * 16 + g * 4 + 3][ecol] = (unsigned short)(u23 >> 16);
    }
    __syncthreads();

    // ---- phase 2: segment reduce via MFMA: C[hid][run] = h^T @ indicator ----
    {
        const int nruns = s_nruns;
        for (int p = 0; p * 16 < nruns; ++p) {
            // indicator B-frags: B[k=edge][n=run] = (runid[edge]==p*16+run)
            union { bf16x8 v; unsigned u[4]; } bfrag[2];
            #pragma unroll
            for (int kh = 0; kh < 2; ++kh)
                #pragma unroll
                for (int ii = 0; ii < 4; ++ii) {
                    int k0 = kh * 32 + g * 8 + ii * 2;
                    unsigned lo = (s_runid[k0]     == p * 16 + arow) ? 0x3F80u : 0u;
                    unsigned hi = (s_runid[k0 + 1] == p * 16 + arow) ? 0x3F80u : 0u;
                    bfrag[kh].u[ii] = lo | (hi << 16);
                }
            const int run16 = p * 16 + arow;
            const bool act  = run16 < nruns;
            const int node  = act ? s_runnode[run16] : 0;
            #pragma unroll
            for (int m = 0; m < 3; ++m) {
                const int mt = w * 3 + m;
                f32x4 acc = (f32x4){0.f, 0.f, 0.f, 0.f};
                #pragma unroll
                for (int kh = 0; kh < 2; ++kh) {
                    bf16x8 a = *(const bf16x8*)&s_hT[mt * 16 + arow][kh * 32 + g * 8];
                    acc = __builtin_amdgcn_mfma_f32_16x16x32_bf16(a, bfrag[kh].v, acc, 0, 0, 0);
                }
                if (act) {
                    float* hb = &Hbar[(size_t)node * DH + mt * 16 + g * 4];
                    atomicAdd(hb + 0, acc[0]);
                    atomicAdd(hb + 1, acc[1]);
                    atomicAdd(hb + 2, acc[2]);
                    atomicAdd(hb + 3, acc[3]);
                }
            }
        }
    }
}

// ---------------------------------------------------------------------------
// node_out v3: one independent wave per 16 rows; counts from row_start (= R15)
// ---------------------------------------------------------------------------
__global__ __launch_bounds__(256) void node_out(
    const float* __restrict__ Hbar, const int* __restrict__ row_start,
    const float* __restrict__ b2, float* __restrict__ out)
{
    const int tid  = threadIdx.x;
    const int lane = tid & 63, w = tid >> 6;
    const int n0   = (blockIdx.x * 4 + w) * 16;
    if (n0 >= NN) return;
    const int arow = lane & 15, akb = (lane >> 4) * 8, rbase = (lane >> 4) * 4;

    const int myrow = (n0 + arow < NN) ? (n0 + arow) : (NN - 1);
    const int cnt = row_start[myrow + 1] - row_start[myrow];
    const float ic = (cnt > 0) ? 1.0f / (float)cnt : 0.0f;

    const float* hrow = Hbar + (size_t)myrow * DH;
    union { bf16x8 v; unsigned u[4]; } a[6];
    #pragma unroll
    for (int kk = 0; kk < 6; ++kk) {
        float4 v0 = *(const float4*)(hrow + kk * 32 + akb);
        float4 v1 = *(const float4*)(hrow + kk * 32 + akb + 4);
        a[kk].u[0] = cvt_pk_bf16(v0.x * ic, v0.y * ic);
        a[kk].u[1] = cvt_pk_bf16(v0.z * ic, v0.w * ic);
        a[kk].u[2] = cvt_pk_bf16(v1.x * ic, v1.y * ic);
        a[kk].u[3] = cvt_pk_bf16(v1.z * ic, v1.w * ic);
    }

    f32x4 acc[8];
    #pragma unroll
    for (int j = 0; j < 8; ++j) acc[j] = (f32x4){0.f, 0.f, 0.f, 0.f};

    #pragma unroll
    for (int kk = 0; kk < 6; ++kk)
        #pragma unroll
        for (int j = 0; j < 8; ++j) {
            bf16x8 b = *(const bf16x8*)(g_p2 + (((size_t)kk * 8 + j) * 64 + lane) * 8);
            acc[j] = __builtin_amdgcn_mfma_f32_16x16x32_bf16(a[kk].v, b, acc[j], 0, 0, 0);
        }

    #pragma unroll
    for (int j = 0; j < 8; ++j) {
        const float bd = b2[j * 16 + arow];
        #pragma unroll
        for (int r = 0; r < 4; ++r) {
            int row = n0 + rbase + r;
            if (row < NN)
                out[(size_t)row * DO + j * 16 + arow] = acc[j][r] + bd;
        }
    }
}

extern "C" void kernel_launch(void* const* d_in, const int* in_sizes, int n_in,
                              void* d_out, int out_size, void* d_ws, size_t ws_size,
                              hipStream_t stream)
{
    const float* n_embed   = (const float*)d_in[0];
    const float* e_embed   = (const float*)d_in[1];
    const int*   senders   = (const int*)d_in[2];
    const int*   receivers = (const int*)d_in[3];
    const float* W1        = (const float*)d_in[4];
    const float* b1        = (const float*)d_in[5];
    const float* W2        = (const float*)d_in[6];
    const float* b2        = (const float*)d_in[7];
    float* out = (float*)d_out;

    unsigned short* Ps   = (unsigned short*)d_ws;             // [NN][192] bf16 (lane-packed)
    unsigned short* Pr   = Ps + (size_t)NN * DH;              // [NN][192] bf16 (lane-packed)
    float*          Hbar = (float*)(Pr + (size_t)NN * DH);    // [NN][192] f32
    int*            row_start = (int*)(Hbar + (size_t)NN * DH);  // [NN+1]

    const int prep_items = FRAGS_TOT + ZH + E_TOT;
    prep<<<(prep_items + 255) / 256, 256, 0, stream>>>(W1, W2, senders, Hbar, row_start);
    node_proj<<<dim3((NN + 63) / 64, 2), 256, 0, stream>>>(n_embed, b1, Ps);
    edge_reduce<<<E_TOT / EB, 256, 0, stream>>>(
        e_embed, senders, receivers, Ps, Pr, Hbar);
    node_out<<<(NN + 63) / 64, 256, 0, stream>>>(Hbar, row_start, b2, out);
}

// Round 19
// 75.410 us; speedup vs baseline: 5.5711x; 1.1351x over previous
//
#include <hip/hip_runtime.h>

#define E_TOT 320000
#define NN    10000
#define DN    128
#define DE    32
#define DH    192
#define DO    128
#define EB    64
#define SHS   196   // s_h row stride in ushorts (392 B)

typedef __attribute__((ext_vector_type(8))) short bf16x8;
typedef __attribute__((ext_vector_type(4))) float f32x4;

// packed weight tables (rewritten every launch); W1-node frags are read
// directly from W1 inside prep_proj (g_p1 deleted -> no cross-block dep)
#define E_FRAGS  (12*64)      // W1_edge^T A-frags (edge GEMM1)
#define W2_FRAGS (6*8*64)     // W2 B-frags (node_out)
#define FRAGS_TOT (E_FRAGS + W2_FRAGS)
#define ZH (NN * DH / 4)      // Hbar zero items (float4)
#define PREP_ITEMS (FRAGS_TOT + ZH + E_TOT)
#define NPROJ (((NN + 63) / 64) * 2)              // 314 node_proj blocks
__device__ __align__(16) unsigned short g_e [E_FRAGS * 8];
__device__ __align__(16) unsigned short g_p2[W2_FRAGS * 8];

__device__ __forceinline__ unsigned short f2bf(float f) {
    union { float f; unsigned u; } v; v.f = f;
    return (unsigned short)((v.u + 0x7FFFu + ((v.u >> 16) & 1u)) >> 16);
}
__device__ __forceinline__ float bflo(unsigned u) {
    union { unsigned v; float f; } t; t.v = u << 16; return t.f;
}
__device__ __forceinline__ float bfhi(unsigned u) {
    union { unsigned v; float f; } t; t.v = u & 0xFFFF0000u; return t.f;
}
__device__ __forceinline__ float bf2f(unsigned short s) {
    union { unsigned v; float f; } t; t.v = (unsigned)s << 16; return t.f;
}
__device__ __forceinline__ float tanh_fast(float x) {
    float ex = __expf(x + x);
    return 1.0f - 2.0f * __builtin_amdgcn_rcpf(ex + 1.0f);
}
__device__ __forceinline__ unsigned cvt_pk_bf16(float lo, float hi) {
    unsigned r;
    asm("v_cvt_pk_bf16_f32 %0, %1, %2" : "=v"(r) : "v"(lo), "v"(hi));
    return r;
}

// ---------------------------------------------------------------------------
// prep_proj: blocks [0,NPROJ) = node projections (direct W1 reads);
//            blocks [NPROJ,..) = pack g_e/g_p2 + zero Hbar + row_start.
// No cross-block dependencies inside this dispatch.
// ---------------------------------------------------------------------------
__global__ __launch_bounds__(256) void prep_proj(
    const float* __restrict__ n_embed, const float* __restrict__ W1,
    const float* __restrict__ W2, const float* __restrict__ b1,
    const int* __restrict__ senders,
    unsigned short* __restrict__ P, float* __restrict__ Hbar,
    int* __restrict__ row_start)
{
    __shared__ __align__(16) unsigned short s_a[64][136];
    const int tid = threadIdx.x;

    if (blockIdx.x >= NPROJ) {
        // ---- prep items ----
        int f = (blockIdx.x - NPROJ) * 256 + tid;
        unsigned short tmp[8];
        if (f < E_FRAGS) {                        // W1_edge^T A-frags
            int mt = f >> 6, lane = f & 63;
            int k0 = ((lane >> 4) << 3);
            int hid = mt * 16 + (lane & 15);
            #pragma unroll
            for (int i = 0; i < 8; ++i) tmp[i] = f2bf(W1[(256 + k0 + i) * DH + hid]);
            *(uint4*)(g_e + (size_t)f * 8) = *(const uint4*)tmp;
        } else if (f < FRAGS_TOT) {               // W2 B-frags
            int f3 = f - E_FRAGS;
            int kk = f3 / (8 * 64), nt = (f3 >> 6) % 8, lane = f3 & 63;
            int r0 = kk * 32 + ((lane >> 4) << 3);
            int c  = nt * 16 + (lane & 15);
            #pragma unroll
            for (int i = 0; i < 8; ++i) tmp[i] = f2bf(W2[(r0 + i) * DO + c]);
            *(uint4*)(g_p2 + (size_t)f3 * 8) = *(const uint4*)tmp;
        } else if (f < FRAGS_TOT + ZH) {          // zero Hbar (float4)
            ((float4*)Hbar)[f - FRAGS_TOT] = make_float4(0.f, 0.f, 0.f, 0.f);
        } else if (f < PREP_ITEMS) {              // row_start builder
            int e = f - FRAGS_TOT - ZH;
            int s_cur  = senders[e];
            int s_prev = (e == 0) ? -1 : senders[e - 1];
            if (s_prev != s_cur)
                for (int n = s_prev + 1; n <= s_cur; ++n) row_start[n] = e;
            if (e == E_TOT - 1)
                for (int n = s_cur + 1; n <= NN; ++n) row_start[n] = E_TOT;
        }
        return;
    }

    // ---- node projections: P'[n][g][mt][i] lane-contiguous layout ----
    const int half = blockIdx.x & 1;
    const int n0   = (blockIdx.x >> 1) * 64;

    #pragma unroll
    for (int it = 0; it < 8; ++it) {
        int idx = tid + it * 256;
        int row = idx >> 5, c = idx & 31;
        float4 v = make_float4(0.f, 0.f, 0.f, 0.f);
        if (n0 + row < NN) v = ((const float4*)(n_embed + (size_t)(n0 + row) * DN))[c];
        unsigned t0 = cvt_pk_bf16(v.x, v.y), t1 = cvt_pk_bf16(v.z, v.w);
        *(uint2*)&s_a[row][c * 4] = make_uint2(t0, t1);
    }
    __syncthreads();

    const int lane = tid & 63, w = tid >> 6;
    const int arow = lane & 15, akb = (lane >> 4) * 8, rbase = (lane >> 4) * 4;

    f32x4 acc[4][3];
    #pragma unroll
    for (int mt = 0; mt < 4; ++mt)
        #pragma unroll
        for (int j = 0; j < 3; ++j) acc[mt][j] = (f32x4){0.f, 0.f, 0.f, 0.f};

    for (int kk = 0; kk < 4; ++kk) {
        bf16x8 a[4];
        union { bf16x8 v; unsigned short t[8]; } b[3];
        #pragma unroll
        for (int mt = 0; mt < 4; ++mt)
            a[mt] = *(const bf16x8*)&s_a[mt * 16 + arow][kk * 32 + akb];
        // direct W1 B-frags: row r0+i = (kk+4*half)*32 + (lane>>4)*8 + i,
        // col = (3w+j)*16 + arow  (same values/rounding as the packed table)
        #pragma unroll
        for (int j = 0; j < 3; ++j) {
            const int r0 = (kk + 4 * half) * 32 + akb;
            const int c  = (3 * w + j) * 16 + arow;
            #pragma unroll
            for (int i = 0; i < 8; ++i) b[j].t[i] = f2bf(W1[(size_t)(r0 + i) * DH + c]);
        }
        #pragma unroll
        for (int mt = 0; mt < 4; ++mt)
            #pragma unroll
            for (int j = 0; j < 3; ++j)
                acc[mt][j] = __builtin_amdgcn_mfma_f32_16x16x32_bf16(a[mt], b[j].v, acc[mt][j], 0, 0, 0);
    }

    unsigned short* Pout = P + (size_t)half * NN * DH;
    float bj[3];
    #pragma unroll
    for (int j = 0; j < 3; ++j) bj[j] = (half == 0) ? b1[48 * w + 16 * j + arow] : 0.f;
    const int gq = arow >> 2, ii = arow & 3;
    #pragma unroll
    for (int mt = 0; mt < 4; ++mt)
        #pragma unroll
        for (int j = 0; j < 3; ++j)
            #pragma unroll
            for (int r = 0; r < 4; ++r) {
                int row = n0 + mt * 16 + rbase + r;
                if (row < NN)
                    Pout[((size_t)row * 4 + gq) * 48 + (3 * w + j) * 4 + ii] =
                        f2bf(acc[mt][j][r] + bj[j]);
            }
}

// ---------------------------------------------------------------------------
// edge kernel (= R15 verbatim): gather + GEMM1^T (P-add in MFMA C-input) +
// tanh -> s_h; one barrier; per-column segment reduce -> RAW sums into Hbar.
// ---------------------------------------------------------------------------
__global__ __launch_bounds__(256) void edge_reduce(
    const float* __restrict__ e_embed,
    const int* __restrict__ senders, const int* __restrict__ receivers,
    const unsigned short* __restrict__ Ps, const unsigned short* __restrict__ Pr,
    float* __restrict__ Hbar)
{
    __shared__ __align__(16) unsigned short s_h[EB][SHS];  // 25088 B
    __shared__ int s_send[EB];

    const int tid  = threadIdx.x;
    const int nb8  = gridDim.x >> 3;                       // 625
    const int e0   = (((blockIdx.x & 7) * nb8) + (blockIdx.x >> 3)) * EB;  // XCD swizzle
    const int lane = tid & 63, w = tid >> 6;
    const int arow = lane & 15, g = lane >> 4;

    // ---- phase 0: per-lane loads (wide, contiguous per lane) ----
    const int myedge = e0 + w * 16 + arow;
    const int sN = senders[myedge], rN = receivers[myedge];
    const unsigned short* psbase = Ps + ((size_t)sN * 4 + g) * 48;
    const unsigned short* prbase = Pr + ((size_t)rN * 4 + g) * 48;
    uint4 psq[6], prq[6];
    #pragma unroll
    for (int j = 0; j < 6; ++j) {
        psq[j] = *(const uint4*)(psbase + j * 8);
        prq[j] = *(const uint4*)(prbase + j * 8);
    }
    union { bf16x8 v; unsigned u[4]; } bfr;
    {
        const float* erow = e_embed + (size_t)myedge * DE + g * 8;
        float4 ev0 = *(const float4*)erow;
        float4 ev1 = *(const float4*)(erow + 4);
        bfr.u[0] = cvt_pk_bf16(ev0.x, ev0.y);
        bfr.u[1] = cvt_pk_bf16(ev0.z, ev0.w);
        bfr.u[2] = cvt_pk_bf16(ev1.x, ev1.y);
        bfr.u[3] = cvt_pk_bf16(ev1.z, ev1.w);
    }
    if (tid < EB) s_send[tid] = senders[e0 + tid];

    // ---- phase 1: GEMM1^T, C-input = Ps+Pr; tanh -> s_h[edge][hid] ----
    #pragma unroll
    for (int mt = 0; mt < 12; ++mt) {
        unsigned px, py, qx, qy;
        if ((mt & 1) == 0) {
            px = psq[mt >> 1].x; py = psq[mt >> 1].y;
            qx = prq[mt >> 1].x; qy = prq[mt >> 1].y;
        } else {
            px = psq[mt >> 1].z; py = psq[mt >> 1].w;
            qx = prq[mt >> 1].z; qy = prq[mt >> 1].w;
        }
        f32x4 cinit;
        cinit[0] = bflo(px) + bflo(qx);
        cinit[1] = bfhi(px) + bfhi(qx);
        cinit[2] = bflo(py) + bflo(qy);
        cinit[3] = bfhi(py) + bfhi(qy);
        bf16x8 af = *(const bf16x8*)(g_e + ((size_t)mt * 64 + lane) * 8);
        f32x4 acc = __builtin_amdgcn_mfma_f32_16x16x32_bf16(af, bfr.v, cinit, 0, 0, 0);
        float t0 = tanh_fast(acc[0]);
        float t1 = tanh_fast(acc[1]);
        float t2 = tanh_fast(acc[2]);
        float t3 = tanh_fast(acc[3]);
        *(uint2*)&s_h[w * 16 + arow][mt * 16 + g * 4] =
            make_uint2(cvt_pk_bf16(t0, t1), cvt_pk_bf16(t2, t3));
    }
    __syncthreads();

    // ---- phase 2: per-column segment reduce of h (sorted senders) -> Hbar ----
    if (tid < DH) {
        const int c = tid;
        float sum = 0.f;
        int cur = s_send[0];
        #pragma unroll 8
        for (int e = 0; e < EB; ++e) {
            sum += bf2f(s_h[e][c]);
            int nxt = (e + 1 < EB) ? s_send[e + 1] : -1;
            if (nxt != cur) {
                atomicAdd(&Hbar[(size_t)cur * DH + c], sum);
                sum = 0.f;
                cur = nxt;
            }
        }
    }
}

// ---------------------------------------------------------------------------
// node_out v3 (= R15 verbatim): one independent wave per 16 rows.
// ---------------------------------------------------------------------------
__global__ __launch_bounds__(256) void node_out(
    const float* __restrict__ Hbar, const int* __restrict__ row_start,
    const float* __restrict__ b2, float* __restrict__ out)
{
    const int tid  = threadIdx.x;
    const int lane = tid & 63, w = tid >> 6;
    const int n0   = (blockIdx.x * 4 + w) * 16;
    if (n0 >= NN) return;
    const int arow = lane & 15, akb = (lane >> 4) * 8, rbase = (lane >> 4) * 4;

    const int myrow = (n0 + arow < NN) ? (n0 + arow) : (NN - 1);
    const int cnt = row_start[myrow + 1] - row_start[myrow];
    const float ic = (cnt > 0) ? 1.0f / (float)cnt : 0.0f;

    const float* hrow = Hbar + (size_t)myrow * DH;
    union { bf16x8 v; unsigned u[4]; } a[6];
    #pragma unroll
    for (int kk = 0; kk < 6; ++kk) {
        float4 v0 = *(const float4*)(hrow + kk * 32 + akb);
        float4 v1 = *(const float4*)(hrow + kk * 32 + akb + 4);
        a[kk].u[0] = cvt_pk_bf16(v0.x * ic, v0.y * ic);
        a[kk].u[1] = cvt_pk_bf16(v0.z * ic, v0.w * ic);
        a[kk].u[2] = cvt_pk_bf16(v1.x * ic, v1.y * ic);
        a[kk].u[3] = cvt_pk_bf16(v1.z * ic, v1.w * ic);
    }

    f32x4 acc[8];
    #pragma unroll
    for (int j = 0; j < 8; ++j) acc[j] = (f32x4){0.f, 0.f, 0.f, 0.f};

    #pragma unroll
    for (int kk = 0; kk < 6; ++kk)
        #pragma unroll
        for (int j = 0; j < 8; ++j) {
            bf16x8 b = *(const bf16x8*)(g_p2 + (((size_t)kk * 8 + j) * 64 + lane) * 8);
            acc[j] = __builtin_amdgcn_mfma_f32_16x16x32_bf16(a[kk].v, b, acc[j], 0, 0, 0);
        }

    #pragma unroll
    for (int j = 0; j < 8; ++j) {
        const float bd = b2[j * 16 + arow];
        #pragma unroll
        for (int r = 0; r < 4; ++r) {
            int row = n0 + rbase + r;
            if (row < NN)
                out[(size_t)row * DO + j * 16 + arow] = acc[j][r] + bd;
        }
    }
}

extern "C" void kernel_launch(void* const* d_in, const int* in_sizes, int n_in,
                              void* d_out, int out_size, void* d_ws, size_t ws_size,
                              hipStream_t stream)
{
    const float* n_embed   = (const float*)d_in[0];
    const float* e_embed   = (const float*)d_in[1];
    const int*   senders   = (const int*)d_in[2];
    const int*   receivers = (const int*)d_in[3];
    const float* W1        = (const float*)d_in[4];
    const float* b1        = (const float*)d_in[5];
    const float* W2        = (const float*)d_in[6];
    const float* b2        = (const float*)d_in[7];
    float* out = (float*)d_out;

    unsigned short* Ps   = (unsigned short*)d_ws;             // [NN][192] bf16 (lane-packed)
    unsigned short* Pr   = Ps + (size_t)NN * DH;              // [NN][192] bf16 (lane-packed)
    float*          Hbar = (float*)(Pr + (size_t)NN * DH);    // [NN][192] f32
    int*            row_start = (int*)(Hbar + (size_t)NN * DH);  // [NN+1]

    const int prep_blocks = (PREP_ITEMS + 255) / 256;         // 3140
    prep_proj<<<NPROJ + prep_blocks, 256, 0, stream>>>(
        n_embed, W1, W2, b1, senders, Ps, Hbar, row_start);
    edge_reduce<<<E_TOT / EB, 256, 0, stream>>>(
        e_embed, senders, receivers, Ps, Pr, Hbar);
    node_out<<<(NN + 63) / 64, 256, 0, stream>>>(Hbar, row_start, b2, out);
}

// Round 20
// 74.899 us; speedup vs baseline: 5.6091x; 1.0068x over previous
//
#include <hip/hip_runtime.h>

#define E_TOT 320000
#define NN    10000
#define DN    128
#define DE    32
#define DH    192
#define DO    128
#define EB    64
#define SHS   196   // s_h row stride in ushorts (392 B)

typedef __attribute__((ext_vector_type(8))) short bf16x8;
typedef __attribute__((ext_vector_type(4))) float f32x4;

// packed weight tables (rewritten every launch); W1-node frags are read
// directly from W1 inside prep_proj (no cross-block dep)
#define E_FRAGS  (12*64)      // W1_edge^T A-frags (edge GEMM1)
#define W2_FRAGS (6*8*64)     // W2 B-frags (node_out)
#define FRAGS_TOT (E_FRAGS + W2_FRAGS)
#define ZH (NN * DH / 4)      // Hbar zero items (float4)
#define PREP_ITEMS (FRAGS_TOT + ZH + E_TOT)
#define NPROJ (((NN + 63) / 64) * 2)              // 314 node_proj blocks
__device__ __align__(16) unsigned short g_e [E_FRAGS * 8];
__device__ __align__(16) unsigned short g_p2[W2_FRAGS * 8];

__device__ __forceinline__ unsigned short f2bf(float f) {
    union { float f; unsigned u; } v; v.f = f;
    return (unsigned short)((v.u + 0x7FFFu + ((v.u >> 16) & 1u)) >> 16);
}
__device__ __forceinline__ float bflo(unsigned u) {
    union { unsigned v; float f; } t; t.v = u << 16; return t.f;
}
__device__ __forceinline__ float bfhi(unsigned u) {
    union { unsigned v; float f; } t; t.v = u & 0xFFFF0000u; return t.f;
}
__device__ __forceinline__ float bf2f(unsigned short s) {
    union { unsigned v; float f; } t; t.v = (unsigned)s << 16; return t.f;
}
__device__ __forceinline__ float tanh_fast(float x) {
    float ex = __expf(x + x);
    return 1.0f - 2.0f * __builtin_amdgcn_rcpf(ex + 1.0f);
}
__device__ __forceinline__ unsigned cvt_pk_bf16(float lo, float hi) {
    unsigned r;
    asm("v_cvt_pk_bf16_f32 %0, %1, %2" : "=v"(r) : "v"(lo), "v"(hi));
    return r;
}

// ---------------------------------------------------------------------------
// prep_proj (= R19 verbatim): blocks [0,NPROJ) node projections (direct W1);
// blocks [NPROJ,..) pack g_e/g_p2 + zero Hbar + row_start.
// ---------------------------------------------------------------------------
__global__ __launch_bounds__(256) void prep_proj(
    const float* __restrict__ n_embed, const float* __restrict__ W1,
    const float* __restrict__ W2, const float* __restrict__ b1,
    const int* __restrict__ senders,
    unsigned short* __restrict__ P, float* __restrict__ Hbar,
    int* __restrict__ row_start)
{
    __shared__ __align__(16) unsigned short s_a[64][136];
    const int tid = threadIdx.x;

    if (blockIdx.x >= NPROJ) {
        int f = (blockIdx.x - NPROJ) * 256 + tid;
        unsigned short tmp[8];
        if (f < E_FRAGS) {
            int mt = f >> 6, lane = f & 63;
            int k0 = ((lane >> 4) << 3);
            int hid = mt * 16 + (lane & 15);
            #pragma unroll
            for (int i = 0; i < 8; ++i) tmp[i] = f2bf(W1[(256 + k0 + i) * DH + hid]);
            *(uint4*)(g_e + (size_t)f * 8) = *(const uint4*)tmp;
        } else if (f < FRAGS_TOT) {
            int f3 = f - E_FRAGS;
            int kk = f3 / (8 * 64), nt = (f3 >> 6) % 8, lane = f3 & 63;
            int r0 = kk * 32 + ((lane >> 4) << 3);
            int c  = nt * 16 + (lane & 15);
            #pragma unroll
            for (int i = 0; i < 8; ++i) tmp[i] = f2bf(W2[(r0 + i) * DO + c]);
            *(uint4*)(g_p2 + (size_t)f3 * 8) = *(const uint4*)tmp;
        } else if (f < FRAGS_TOT + ZH) {
            ((float4*)Hbar)[f - FRAGS_TOT] = make_float4(0.f, 0.f, 0.f, 0.f);
        } else if (f < PREP_ITEMS) {
            int e = f - FRAGS_TOT - ZH;
            int s_cur  = senders[e];
            int s_prev = (e == 0) ? -1 : senders[e - 1];
            if (s_prev != s_cur)
                for (int n = s_prev + 1; n <= s_cur; ++n) row_start[n] = e;
            if (e == E_TOT - 1)
                for (int n = s_cur + 1; n <= NN; ++n) row_start[n] = E_TOT;
        }
        return;
    }

    const int half = blockIdx.x & 1;
    const int n0   = (blockIdx.x >> 1) * 64;

    #pragma unroll
    for (int it = 0; it < 8; ++it) {
        int idx = tid + it * 256;
        int row = idx >> 5, c = idx & 31;
        float4 v = make_float4(0.f, 0.f, 0.f, 0.f);
        if (n0 + row < NN) v = ((const float4*)(n_embed + (size_t)(n0 + row) * DN))[c];
        unsigned t0 = cvt_pk_bf16(v.x, v.y), t1 = cvt_pk_bf16(v.z, v.w);
        *(uint2*)&s_a[row][c * 4] = make_uint2(t0, t1);
    }
    __syncthreads();

    const int lane = tid & 63, w = tid >> 6;
    const int arow = lane & 15, akb = (lane >> 4) * 8, rbase = (lane >> 4) * 4;

    f32x4 acc[4][3];
    #pragma unroll
    for (int mt = 0; mt < 4; ++mt)
        #pragma unroll
        for (int j = 0; j < 3; ++j) acc[mt][j] = (f32x4){0.f, 0.f, 0.f, 0.f};

    for (int kk = 0; kk < 4; ++kk) {
        bf16x8 a[4];
        union { bf16x8 v; unsigned short t[8]; } b[3];
        #pragma unroll
        for (int mt = 0; mt < 4; ++mt)
            a[mt] = *(const bf16x8*)&s_a[mt * 16 + arow][kk * 32 + akb];
        #pragma unroll
        for (int j = 0; j < 3; ++j) {
            const int r0 = (kk + 4 * half) * 32 + akb;
            const int c  = (3 * w + j) * 16 + arow;
            #pragma unroll
            for (int i = 0; i < 8; ++i) b[j].t[i] = f2bf(W1[(size_t)(r0 + i) * DH + c]);
        }
        #pragma unroll
        for (int mt = 0; mt < 4; ++mt)
            #pragma unroll
            for (int j = 0; j < 3; ++j)
                acc[mt][j] = __builtin_amdgcn_mfma_f32_16x16x32_bf16(a[mt], b[j].v, acc[mt][j], 0, 0, 0);
    }

    unsigned short* Pout = P + (size_t)half * NN * DH;
    float bj[3];
    #pragma unroll
    for (int j = 0; j < 3; ++j) bj[j] = (half == 0) ? b1[48 * w + 16 * j + arow] : 0.f;
    const int gq = arow >> 2, ii = arow & 3;
    #pragma unroll
    for (int mt = 0; mt < 4; ++mt)
        #pragma unroll
        for (int j = 0; j < 3; ++j)
            #pragma unroll
            for (int r = 0; r < 4; ++r) {
                int row = n0 + mt * 16 + rbase + r;
                if (row < NN)
                    Pout[((size_t)row * 4 + gq) * 48 + (3 * w + j) * 4 + ii] =
                        f2bf(acc[mt][j][r] + bj[j]);
            }
}

// ---------------------------------------------------------------------------
// edge kernel: R19 with ONE delta — phase 2 splits into {32 batched loads ->
// registers} then {pure-register run-walk}, twice. Breaks the 64-step
// dependent LDS-latency chain (T14 issue-early/consume-late).
// ---------------------------------------------------------------------------
__global__ __launch_bounds__(256) void edge_reduce(
    const float* __restrict__ e_embed,
    const int* __restrict__ senders, const int* __restrict__ receivers,
    const unsigned short* __restrict__ Ps, const unsigned short* __restrict__ Pr,
    float* __restrict__ Hbar)
{
    __shared__ __align__(16) unsigned short s_h[EB][SHS];  // 25088 B
    __shared__ int s_send[EB];

    const int tid  = threadIdx.x;
    const int nb8  = gridDim.x >> 3;                       // 625
    const int e0   = (((blockIdx.x & 7) * nb8) + (blockIdx.x >> 3)) * EB;  // XCD swizzle
    const int lane = tid & 63, w = tid >> 6;
    const int arow = lane & 15, g = lane >> 4;

    // ---- phase 0: per-lane loads (wide, contiguous per lane) ----
    const int myedge = e0 + w * 16 + arow;
    const int sN = senders[myedge], rN = receivers[myedge];
    const unsigned short* psbase = Ps + ((size_t)sN * 4 + g) * 48;
    const unsigned short* prbase = Pr + ((size_t)rN * 4 + g) * 48;
    uint4 psq[6], prq[6];
    #pragma unroll
    for (int j = 0; j < 6; ++j) {
        psq[j] = *(const uint4*)(psbase + j * 8);
        prq[j] = *(const uint4*)(prbase + j * 8);
    }
    union { bf16x8 v; unsigned u[4]; } bfr;
    {
        const float* erow = e_embed + (size_t)myedge * DE + g * 8;
        float4 ev0 = *(const float4*)erow;
        float4 ev1 = *(const float4*)(erow + 4);
        bfr.u[0] = cvt_pk_bf16(ev0.x, ev0.y);
        bfr.u[1] = cvt_pk_bf16(ev0.z, ev0.w);
        bfr.u[2] = cvt_pk_bf16(ev1.x, ev1.y);
        bfr.u[3] = cvt_pk_bf16(ev1.z, ev1.w);
    }
    if (tid < EB) s_send[tid] = senders[e0 + tid];

    // ---- phase 1: GEMM1^T, C-input = Ps+Pr; tanh -> s_h[edge][hid] ----
    #pragma unroll
    for (int mt = 0; mt < 12; ++mt) {
        unsigned px, py, qx, qy;
        if ((mt & 1) == 0) {
            px = psq[mt >> 1].x; py = psq[mt >> 1].y;
            qx = prq[mt >> 1].x; qy = prq[mt >> 1].y;
        } else {
            px = psq[mt >> 1].z; py = psq[mt >> 1].w;
            qx = prq[mt >> 1].z; qy = prq[mt >> 1].w;
        }
        f32x4 cinit;
        cinit[0] = bflo(px) + bflo(qx);
        cinit[1] = bfhi(px) + bfhi(qx);
        cinit[2] = bflo(py) + bflo(qy);
        cinit[3] = bfhi(py) + bfhi(qy);
        bf16x8 af = *(const bf16x8*)(g_e + ((size_t)mt * 64 + lane) * 8);
        f32x4 acc = __builtin_amdgcn_mfma_f32_16x16x32_bf16(af, bfr.v, cinit, 0, 0, 0);
        float t0 = tanh_fast(acc[0]);
        float t1 = tanh_fast(acc[1]);
        float t2 = tanh_fast(acc[2]);
        float t3 = tanh_fast(acc[3]);
        *(uint2*)&s_h[w * 16 + arow][mt * 16 + g * 4] =
            make_uint2(cvt_pk_bf16(t0, t1), cvt_pk_bf16(t2, t3));
    }
    __syncthreads();

    // ---- phase 2: batched-preload segment reduce (sorted senders) -> Hbar ----
    if (tid < DH) {
        const int c = tid;
        float sum = 0.f;
        int cur = s_send[0];
        #pragma unroll
        for (int half = 0; half < 2; ++half) {
            // (a) 32 independent loads -> registers (scheduler hoists them)
            float vals[32];
            #pragma unroll
            for (int k = 0; k < 32; ++k)
                vals[k] = bf2f(s_h[half * 32 + k][c]);
            // (b) pure-register run-walk
            #pragma unroll
            for (int k = 0; k < 32; ++k) {
                int e = half * 32 + k;
                sum += vals[k];
                int nxt = (e + 1 < EB) ? s_send[e + 1] : -1;
                if (nxt != cur) {
                    atomicAdd(&Hbar[(size_t)cur * DH + c], sum);
                    sum = 0.f;
                    cur = nxt;
                }
            }
        }
    }
}

// ---------------------------------------------------------------------------
// node_out v3 (= R19 verbatim): one independent wave per 16 rows.
// ---------------------------------------------------------------------------
__global__ __launch_bounds__(256) void node_out(
    const float* __restrict__ Hbar, const int* __restrict__ row_start,
    const float* __restrict__ b2, float* __restrict__ out)
{
    const int tid  = threadIdx.x;
    const int lane = tid & 63, w = tid >> 6;
    const int n0   = (blockIdx.x * 4 + w) * 16;
    if (n0 >= NN) return;
    const int arow = lane & 15, akb = (lane >> 4) * 8, rbase = (lane >> 4) * 4;

    const int myrow = (n0 + arow < NN) ? (n0 + arow) : (NN - 1);
    const int cnt = row_start[myrow + 1] - row_start[myrow];
    const float ic = (cnt > 0) ? 1.0f / (float)cnt : 0.0f;

    const float* hrow = Hbar + (size_t)myrow * DH;
    union { bf16x8 v; unsigned u[4]; } a[6];
    #pragma unroll
    for (int kk = 0; kk < 6; ++kk) {
        float4 v0 = *(const float4*)(hrow + kk * 32 + akb);
        float4 v1 = *(const float4*)(hrow + kk * 32 + akb + 4);
        a[kk].u[0] = cvt_pk_bf16(v0.x * ic, v0.y * ic);
        a[kk].u[1] = cvt_pk_bf16(v0.z * ic, v0.w * ic);
        a[kk].u[2] = cvt_pk_bf16(v1.x * ic, v1.y * ic);
        a[kk].u[3] = cvt_pk_bf16(v1.z * ic, v1.w * ic);
    }

    f32x4 acc[8];
    #pragma unroll
    for (int j = 0; j < 8; ++j) acc[j] = (f32x4){0.f, 0.f, 0.f, 0.f};

    #pragma unroll
    for (int kk = 0; kk < 6; ++kk)
        #pragma unroll
        for (int j = 0; j < 8; ++j) {
            bf16x8 b = *(const bf16x8*)(g_p2 + (((size_t)kk * 8 + j) * 64 + lane) * 8);
            acc[j] = __builtin_amdgcn_mfma_f32_16x16x32_bf16(a[kk].v, b, acc[j], 0, 0, 0);
        }

    #pragma unroll
    for (int j = 0; j < 8; ++j) {
        const float bd = b2[j * 16 + arow];
        #pragma unroll
        for (int r = 0; r < 4; ++r) {
            int row = n0 + rbase + r;
            if (row < NN)
                out[(size_t)row * DO + j * 16 + arow] = acc[j][r] + bd;
        }
    }
}

extern "C" void kernel_launch(void* const* d_in, const int* in_sizes, int n_in,
                              void* d_out, int out_size, void* d_ws, size_t ws_size,
                              hipStream_t stream)
{
    const float* n_embed   = (const float*)d_in[0];
    const float* e_embed   = (const float*)d_in[1];
    const int*   senders   = (const int*)d_in[2];
    const int*   receivers = (const int*)d_in[3];
    const float* W1        = (const float*)d_in[4];
    const float* b1        = (const float*)d_in[5];
    const float* W2        = (const float*)d_in[6];
    const float* b2        = (const float*)d_in[7];
    float* out = (float*)d_out;

    unsigned short* Ps   = (unsigned short*)d_ws;             // [NN][192] bf16 (lane-packed)
    unsigned short* Pr   = Ps + (size_t)NN * DH;              // [NN][192] bf16 (lane-packed)
    float*          Hbar = (float*)(Pr + (size_t)NN * DH);    // [NN][192] f32
    int*            row_start = (int*)(Hbar + (size_t)NN * DH);  // [NN+1]

    const int prep_blocks = (PREP_ITEMS + 255) / 256;         // 3140
    prep_proj<<<NPROJ + prep_blocks, 256, 0, stream>>>(
        n_embed, W1, W2, b1, senders, Ps, Hbar, row_start);
    edge_reduce<<<E_TOT / EB, 256, 0, stream>>>(
        e_embed, senders, receivers, Ps, Pr, Hbar);
    node_out<<<(NN + 63) / 64, 256, 0, stream>>>(Hbar, row_start, b2, out);
}